// Round 6
// baseline (1136.164 us; speedup 1.0000x reference)
//
#include <hip/hip_runtime.h>
#include <hip/hip_bf16.h>

#define SEQ_T 784
#define HID   128

typedef __attribute__((ext_vector_type(8))) short  short8;
typedef __attribute__((ext_vector_type(4))) short  shortx4;
typedef __attribute__((ext_vector_type(4))) float  floatx4;
typedef __attribute__((ext_vector_type(8))) float  float8;

// bf16 round-to-nearest-even on raw bits (inputs finite)
static __device__ __forceinline__ short bf16_of(float f) {
  union { float f; unsigned u; } v; v.f = f;
  return (short)((v.u + 0x7fffu + ((v.u >> 16) & 1u)) >> 16);
}
static __device__ __forceinline__ float f_of_bf16(short s) {
  union { unsigned u; float f; } v; v.u = ((unsigned)(unsigned short)s) << 16;
  return v.f;
}

// Dense 16-row GRU block: 64 blocks x 16 batch rows, 512 threads (8 waves).
// Wave wv owns gate-columns j = wv*16 + (lane&15). MFMA 16x16x32 bf16,
// split-precision (hi/lo) h and Wh -> 3 passes -> fp32-faithful recurrence.
// C/D map row=(lane>>4)*4+reg, col=lane&15 verified on-silicon by the R5
// runtime probe (bit-identical result to the assumed map).
extern "C" __global__ void __launch_bounds__(512, 2)
gru_dense16(const float* __restrict__ x,    // [1024][784] fp32
            const float* __restrict__ Wi,   // [384]
            const float* __restrict__ bi,   // [384]
            const float* __restrict__ Wh,   // [384][128]
            const float* __restrict__ bh,   // [384]
            const float* __restrict__ Wfc,  // [10][128]
            const float* __restrict__ bfc,  // [10]
            float* __restrict__ out)        // [1024][10] fp32  <-- the fix
{
  const int tid  = threadIdx.x;
  const int wv   = tid >> 6;
  const int lane = tid & 63;
  const int quad = lane >> 4;        // C rows 4*quad+0..3 live in regs 0..3
  const int nn   = lane & 15;        // A row m / C col
  const int j    = (wv << 4) | nn;   // gate column 0..127
  const int b0   = blockIdx.x * 16;  // 16 batch rows per block

  __shared__ __align__(16) short xs_t[SEQ_T][16];      // x as bf16, [t][row]
  __shared__ __align__(16) short hbh[2][16 * 136];     // h_hi plane, A-layout, dbuf
  __shared__ __align__(16) short hbl[2][16 * 136];     // h_lo plane
  __shared__ float hfin[16][HID];

  for (int i = tid; i < 16 * 136; i += 512) {
    hbh[0][i] = 0; hbh[1][i] = 0; hbl[0][i] = 0; hbl[1][i] = 0;
  }
  for (int i = tid; i < 16 * SEQ_T; i += 512) {
    const int r = i / SEQ_T;
    const int t = i - r * SEQ_T;
    xs_t[t][r] = bf16_of(x[(size_t)(b0 + r) * SEQ_T + t]);
  }

  // fp32 per-column gate constants
  const float wi_r = Wi[j],  wi_z = Wi[HID + j],  wi_n = Wi[2 * HID + j];
  const float bi_r = bi[j],  bi_z = bi[HID + j],  bi_n = bi[2 * HID + j];
  const float bh_r = bh[j],  bh_z = bh[HID + j],  bh_n = bh[2 * HID + j];

  // Wh B-fragments (hi/lo bf16 split), register-resident for the whole scan.
  // Lane (quad,nn): B[k = kk*32 + quad*8 + e][n = nn] = Wh[j][k]  (B^T rows)
  short8 whi[3][4], wlo[3][4];
  #pragma unroll
  for (int g = 0; g < 3; ++g) {
    const float* wrow = Wh + (size_t)(g * HID + j) * HID;
    #pragma unroll
    for (int kk = 0; kk < 4; ++kk) {
      float8 w = *(const float8*)(wrow + kk * 32 + quad * 8);
      short8 hi, lo;
      #pragma unroll
      for (int e = 0; e < 8; ++e) {
        short h = bf16_of(w[e]);
        hi[e] = h;
        lo[e] = bf16_of(w[e] - f_of_bf16(h));
      }
      whi[g][kk] = hi; wlo[g][kk] = lo;
    }
  }

  float hreg[4] = {0.f, 0.f, 0.f, 0.f};   // h[4*quad+r][j], fp32 carry
  const int a_off = nn * 136 + quad * 8;  // + kk*32 (shorts): A[m=nn][k]
  const int w_row = quad * 4;             // rows written by this lane

  __syncthreads();

  for (int t = 0; t < SEQ_T; ++t) {
    const short* hch = hbh[t & 1];
    const short* hcl = hbl[t & 1];
    short8 ah[4], al[4];
    #pragma unroll
    for (int kk = 0; kk < 4; ++kk) {
      ah[kk] = *(const short8*)(hch + a_off + kk * 32);
      al[kk] = *(const short8*)(hcl + a_off + kk * 32);
    }

    floatx4 ar = {0.f, 0.f, 0.f, 0.f};
    floatx4 az = {0.f, 0.f, 0.f, 0.f};
    floatx4 an = {0.f, 0.f, 0.f, 0.f};
    #pragma unroll
    for (int kk = 0; kk < 4; ++kk) {   // pass 1: h_hi * W_hi
      ar = __builtin_amdgcn_mfma_f32_16x16x32_bf16(ah[kk], whi[0][kk], ar, 0, 0, 0);
      az = __builtin_amdgcn_mfma_f32_16x16x32_bf16(ah[kk], whi[1][kk], az, 0, 0, 0);
      an = __builtin_amdgcn_mfma_f32_16x16x32_bf16(ah[kk], whi[2][kk], an, 0, 0, 0);
    }
    #pragma unroll
    for (int kk = 0; kk < 4; ++kk) {   // pass 2: h_hi * W_lo
      ar = __builtin_amdgcn_mfma_f32_16x16x32_bf16(ah[kk], wlo[0][kk], ar, 0, 0, 0);
      az = __builtin_amdgcn_mfma_f32_16x16x32_bf16(ah[kk], wlo[1][kk], az, 0, 0, 0);
      an = __builtin_amdgcn_mfma_f32_16x16x32_bf16(ah[kk], wlo[2][kk], an, 0, 0, 0);
    }
    #pragma unroll
    for (int kk = 0; kk < 4; ++kk) {   // pass 3: h_lo * W_hi
      ar = __builtin_amdgcn_mfma_f32_16x16x32_bf16(al[kk], whi[0][kk], ar, 0, 0, 0);
      az = __builtin_amdgcn_mfma_f32_16x16x32_bf16(al[kk], whi[1][kk], az, 0, 0, 0);
      an = __builtin_amdgcn_mfma_f32_16x16x32_bf16(al[kk], whi[2][kk], an, 0, 0, 0);
    }

    // reg r holds C[4*quad + r][nn] -> batch row 4*quad+r, column j
    const shortx4 xt4 = *(const shortx4*)&xs_t[t][quad * 4];
    short* nxh = hbh[(t + 1) & 1];
    short* nxl = hbl[(t + 1) & 1];
    #pragma unroll
    for (int r = 0; r < 4; ++r) {
      const float xt = f_of_bf16(xt4[r]);
      const float pr = fmaf(xt, wi_r, bi_r) + ar[r] + bh_r;
      const float pz = fmaf(xt, wi_z, bi_z) + az[r] + bh_z;
      const float rg = 1.0f / (1.0f + __expf(-pr));
      const float zg = 1.0f / (1.0f + __expf(-pz));
      const float pn = fmaf(rg, an[r] + bh_n, fmaf(xt, wi_n, bi_n));
      const float ng = 1.0f - 2.0f / (1.0f + __expf(2.0f * pn));  // tanh
      hreg[r] = fmaf(zg, hreg[r] - ng, ng);    // z*h + (1-z)*n
      const short hh = bf16_of(hreg[r]);
      nxh[(w_row + r) * 136 + j] = hh;
      nxl[(w_row + r) * 136 + j] = bf16_of(hreg[r] - f_of_bf16(hh));
    }
    __syncthreads();
  }

  // epilogue: logits = h @ Wfc^T + bfc (fp32), 16 rows x 10 outs
  #pragma unroll
  for (int r = 0; r < 4; ++r) hfin[w_row + r][j] = hreg[r];
  __syncthreads();
  if (tid < 160) {
    const int r = tid / 10, o = tid - r * 10;
    float acc = bfc[o];
    #pragma unroll 4
    for (int k = 0; k < HID; ++k)
      acc = fmaf(hfin[r][k], Wfc[o * HID + k], acc);
    out[(size_t)(b0 + r) * 10 + o] = acc;     // fp32 store
  }
}

extern "C" void kernel_launch(void* const* d_in, const int* in_sizes, int n_in,
                              void* d_out, int out_size, void* d_ws, size_t ws_size,
                              hipStream_t stream) {
  const float* x   = (const float*)d_in[0];
  const float* Wi  = (const float*)d_in[1];
  const float* bi  = (const float*)d_in[2];
  const float* Wh  = (const float*)d_in[3];
  const float* bh  = (const float*)d_in[4];
  const float* Wfc = (const float*)d_in[5];
  const float* bfc = (const float*)d_in[6];
  hipLaunchKernelGGL(gru_dense16, dim3(64), dim3(512), 0, stream,
                     x, Wi, bi, Wh, bh, Wfc, bfc, (float*)d_out);
}

// Round 7
// 720.035 us; speedup vs baseline: 1.5779x; 1.5779x over previous
//
#include <hip/hip_runtime.h>
#include <hip/hip_bf16.h>

#define SEQ_T 784
#define HID   128

typedef __attribute__((ext_vector_type(8))) short  short8;
typedef __attribute__((ext_vector_type(4))) float  floatx4;
typedef __attribute__((ext_vector_type(8))) float  float8;

// bf16 round-to-nearest-even on raw bits (inputs finite)
static __device__ __forceinline__ short bf16_of(float f) {
  union { float f; unsigned u; } v; v.f = f;
  return (short)((v.u + 0x7fffu + ((v.u >> 16) & 1u)) >> 16);
}
static __device__ __forceinline__ float f_of_bf16(short s) {
  union { unsigned u; float f; } v; v.u = ((unsigned)(unsigned short)s) << 16;
  return v.f;
}

// 256 blocks x 4 batch rows: every CU active. Batch row r lives at A-row 4r
// (A rows != 0 mod 4 are zero => C rows 4q+1..3 are zero and unused; C reg 0
// of lane(quad,nn) = batch row quad, column j). Split-precision (hi/lo) h and
// Wh -> 3 MFMA passes -> fp32-faithful recurrence (R6: absmax 9.8e-4).
// h LDS: 4 compact slots, stride 160 shorts (=80 dwords == 16 mod 32 banks:
// 2-way max on b128 reads/b16 writes -> conflict-free per m136).
extern "C" __global__ void __launch_bounds__(512, 2)
gru_sparse4(const float* __restrict__ x,    // [1024][784] fp32
            const float* __restrict__ Wi,   // [384]
            const float* __restrict__ bi,   // [384]
            const float* __restrict__ Wh,   // [384][128]
            const float* __restrict__ bh,   // [384]
            const float* __restrict__ Wfc,  // [10][128]
            const float* __restrict__ bfc,  // [10]
            float* __restrict__ out)        // [1024][10] fp32
{
  const int tid  = threadIdx.x;
  const int wv   = tid >> 6;
  const int lane = tid & 63;
  const int quad = lane >> 4;
  const int nn   = lane & 15;
  const int j    = (wv << 4) | nn;   // this lane's hidden column
  const int b0   = blockIdx.x * 4;   // 4 batch rows per block

  __shared__ __align__(16) float xs[SEQ_T][4];        // x fp32, [t][row]
  __shared__ __align__(16) short hbh[2][4 * 160];     // h_hi, 4 slots, dbuf
  __shared__ __align__(16) short hbl[2][4 * 160];     // h_lo
  __shared__ float hfin[4][HID];

  for (int i = tid; i < 2 * 4 * 160; i += 512) {
    ((short*)hbh)[i] = 0; ((short*)hbl)[i] = 0;
  }
  for (int i = tid; i < 4 * SEQ_T; i += 512) {
    const int r = i / SEQ_T;            // row-major per r: coalesced global reads
    const int t = i - r * SEQ_T;
    xs[t][r] = x[(size_t)(b0 + r) * SEQ_T + t];
  }

  // fp32 per-column gate constants (lane owns batch row quad, column j)
  const float wi_r = Wi[j],  wi_z = Wi[HID + j],  wi_n = Wi[2 * HID + j];
  const float bi_r = bi[j],  bi_z = bi[HID + j],  bi_n = bi[2 * HID + j];
  const float bh_r = bh[j],  bh_z = bh[HID + j],  bh_n = bh[2 * HID + j];

  // Wh B-fragments (hi/lo bf16 split), register-resident for the whole scan.
  // Lane (quad,nn): B[k = kk*32 + quad*8 + e][n = nn] = Wh[j][k]
  short8 whi[3][4], wlo[3][4];
  #pragma unroll
  for (int g = 0; g < 3; ++g) {
    const float* wrow = Wh + (size_t)(g * HID + j) * HID;
    #pragma unroll
    for (int kk = 0; kk < 4; ++kk) {
      float8 w = *(const float8*)(wrow + kk * 32 + quad * 8);
      short8 hi, lo;
      #pragma unroll
      for (int e = 0; e < 8; ++e) {
        short h = bf16_of(w[e]);
        hi[e] = h;
        lo[e] = bf16_of(w[e] - f_of_bf16(h));
      }
      whi[g][kk] = hi; wlo[g][kk] = lo;
    }
  }

  float h = 0.0f;                          // h[batch=quad][j], fp32 carry
  const bool aact  = ((nn & 3) == 0);      // A rows 0,4,8,12 hold batch rows
  const int  a_off = (nn >> 2) * 160 + quad * 8;  // + kk*32 (shorts)
  const int  w_off = quad * 160 + j;
  const short8 zero8 = {0, 0, 0, 0, 0, 0, 0, 0};

  __syncthreads();

  for (int t = 0; t < SEQ_T; ++t) {
    const short* hch = hbh[t & 1];
    const short* hcl = hbl[t & 1];
    short8 ah[4], al[4];
    #pragma unroll
    for (int kk = 0; kk < 4; ++kk) {
      ah[kk] = aact ? *(const short8*)(hch + a_off + kk * 32) : zero8;
      al[kk] = aact ? *(const short8*)(hcl + a_off + kk * 32) : zero8;
    }

    floatx4 ar = {0.f, 0.f, 0.f, 0.f};
    floatx4 az = {0.f, 0.f, 0.f, 0.f};
    floatx4 an = {0.f, 0.f, 0.f, 0.f};
    #pragma unroll
    for (int kk = 0; kk < 4; ++kk) {   // pass 1: h_hi * W_hi
      ar = __builtin_amdgcn_mfma_f32_16x16x32_bf16(ah[kk], whi[0][kk], ar, 0, 0, 0);
      az = __builtin_amdgcn_mfma_f32_16x16x32_bf16(ah[kk], whi[1][kk], az, 0, 0, 0);
      an = __builtin_amdgcn_mfma_f32_16x16x32_bf16(ah[kk], whi[2][kk], an, 0, 0, 0);
    }
    #pragma unroll
    for (int kk = 0; kk < 4; ++kk) {   // pass 2: h_hi * W_lo
      ar = __builtin_amdgcn_mfma_f32_16x16x32_bf16(ah[kk], wlo[0][kk], ar, 0, 0, 0);
      az = __builtin_amdgcn_mfma_f32_16x16x32_bf16(ah[kk], wlo[1][kk], az, 0, 0, 0);
      an = __builtin_amdgcn_mfma_f32_16x16x32_bf16(ah[kk], wlo[2][kk], an, 0, 0, 0);
    }
    #pragma unroll
    for (int kk = 0; kk < 4; ++kk) {   // pass 3: h_lo * W_hi
      ar = __builtin_amdgcn_mfma_f32_16x16x32_bf16(al[kk], whi[0][kk], ar, 0, 0, 0);
      az = __builtin_amdgcn_mfma_f32_16x16x32_bf16(al[kk], whi[1][kk], az, 0, 0, 0);
      an = __builtin_amdgcn_mfma_f32_16x16x32_bf16(al[kk], whi[2][kk], an, 0, 0, 0);
    }

    // C reg 0 = batch row quad, column j. Full wave active.
    const float xt = xs[t][quad];
    const float pr = fmaf(xt, wi_r, bi_r) + ar[0] + bh_r;
    const float pz = fmaf(xt, wi_z, bi_z) + az[0] + bh_z;
    const float rg = __builtin_amdgcn_rcpf(1.0f + __expf(-pr));
    const float zg = __builtin_amdgcn_rcpf(1.0f + __expf(-pz));
    const float pn = fmaf(rg, an[0] + bh_n, fmaf(xt, wi_n, bi_n));
    const float ng = 1.0f - 2.0f * __builtin_amdgcn_rcpf(1.0f + __expf(2.0f * pn));
    h = fmaf(zg, h - ng, ng);          // z*h + (1-z)*n
    const short hh = bf16_of(h);
    hbh[(t + 1) & 1][w_off] = hh;
    hbl[(t + 1) & 1][w_off] = bf16_of(h - f_of_bf16(hh));
    __syncthreads();
  }

  // epilogue: logits = h @ Wfc^T + bfc (fp32), 4 rows x 10 outs
  hfin[quad][j] = h;
  __syncthreads();
  if (tid < 40) {
    const int r = tid / 10, o = tid - r * 10;
    float acc = bfc[o];
    #pragma unroll 4
    for (int k = 0; k < HID; ++k)
      acc = fmaf(hfin[r][k], Wfc[o * HID + k], acc);
    out[(size_t)(b0 + r) * 10 + o] = acc;
  }
}

extern "C" void kernel_launch(void* const* d_in, const int* in_sizes, int n_in,
                              void* d_out, int out_size, void* d_ws, size_t ws_size,
                              hipStream_t stream) {
  const float* x   = (const float*)d_in[0];
  const float* Wi  = (const float*)d_in[1];
  const float* bi  = (const float*)d_in[2];
  const float* Wh  = (const float*)d_in[3];
  const float* bh  = (const float*)d_in[4];
  const float* Wfc = (const float*)d_in[5];
  const float* bfc = (const float*)d_in[6];
  hipLaunchKernelGGL(gru_sparse4, dim3(256), dim3(512), 0, stream,
                     x, Wi, bi, Wh, bh, Wfc, bfc, (float*)d_out);
}

// Round 8
// 543.406 us; speedup vs baseline: 2.0908x; 1.3250x over previous
//
#include <hip/hip_runtime.h>
#include <hip/hip_bf16.h>

#define SEQ_T 784
#define HID   128

typedef __attribute__((ext_vector_type(8))) short  short8;
typedef __attribute__((ext_vector_type(4))) float  floatx4;
typedef __attribute__((ext_vector_type(8))) float  float8;

// bf16 round-to-nearest-even on raw bits (inputs finite)
static __device__ __forceinline__ short bf16_of(float f) {
  union { float f; unsigned u; } v; v.f = f;
  return (short)((v.u + 0x7fffu + ((v.u >> 16) & 1u)) >> 16);
}
static __device__ __forceinline__ float f_of_bf16(short s) {
  union { unsigned u; float f; } v; v.u = ((unsigned)(unsigned short)s) << 16;
  return v.f;
}

// 256 blocks x 4 batch rows (1 block/CU). Batch row r at A-row 4r; C reg 0 of
// lane(quad,nn) = batch row quad, column j (R5 probe-verified map).
// K=256-packed 2-pass matmul: gh = bf16(h) * (W_hi + W_lo) -- W exact to fp32,
// only h quantized (random ~1e-4/step, z-contracted). 24 MFMA/wave/step in six
// independent depth-4 chains (was 36 in depth-12 chains).
extern "C" __global__ void __launch_bounds__(512, 2)
gru_sparse4_w2(const float* __restrict__ x,    // [1024][784] fp32
               const float* __restrict__ Wi,   // [384]
               const float* __restrict__ bi,   // [384]
               const float* __restrict__ Wh,   // [384][128]
               const float* __restrict__ bh,   // [384]
               const float* __restrict__ Wfc,  // [10][128]
               const float* __restrict__ bfc,  // [10]
               float* __restrict__ out)        // [1024][10] fp32
{
  const int tid  = threadIdx.x;
  const int wv   = tid >> 6;
  const int lane = tid & 63;
  const int quad = lane >> 4;
  const int nn   = lane & 15;
  const int j    = (wv << 4) | nn;   // this lane's hidden column
  const int b0   = blockIdx.x * 4;   // 4 batch rows per block

  __shared__ __align__(16) float xs[SEQ_T][4];        // x fp32, [t][row]
  __shared__ __align__(16) short hb[2][4 * 160];      // h bf16, 4 slots, dbuf
  __shared__ float hfin[4][HID];

  for (int i = tid; i < 2 * 4 * 160; i += 512) ((short*)hb)[i] = 0;
  for (int i = tid; i < 4 * SEQ_T; i += 512) {
    const int r = i / SEQ_T;
    const int t = i - r * SEQ_T;
    xs[t][r] = x[(size_t)(b0 + r) * SEQ_T + t];
  }

  // fp32 per-column gate constants (lane owns batch row quad, column j)
  const float wi_r = Wi[j],  wi_z = Wi[HID + j],  wi_n = Wi[2 * HID + j];
  const float bi_r = bi[j],  bi_z = bi[HID + j],  bi_n = bi[2 * HID + j];
  const float bh_r = bh[j],  bh_z = bh[HID + j],  bh_n = bh[2 * HID + j];

  // Wh B-fragments, hi/lo bf16 split (W_hi + W_lo == W to ~2^-17), register-
  // resident. Lane (quad,nn): B[k = kk*32 + quad*8 + e][n = nn] = Wh[j][k]
  short8 whi[3][4], wlo[3][4];
  #pragma unroll
  for (int g = 0; g < 3; ++g) {
    const float* wrow = Wh + (size_t)(g * HID + j) * HID;
    #pragma unroll
    for (int kk = 0; kk < 4; ++kk) {
      float8 w = *(const float8*)(wrow + kk * 32 + quad * 8);
      short8 hi, lo;
      #pragma unroll
      for (int e = 0; e < 8; ++e) {
        short h = bf16_of(w[e]);
        hi[e] = h;
        lo[e] = bf16_of(w[e] - f_of_bf16(h));
      }
      whi[g][kk] = hi; wlo[g][kk] = lo;
    }
  }

  float h = 0.0f;                          // h[batch=quad][j], fp32 carry
  const bool aact  = ((nn & 3) == 0);      // A rows 0,4,8,12 hold batch rows
  const int  a_off = (nn >> 2) * 160 + quad * 8;  // + kk*32 (shorts)
  const int  w_off = quad * 160 + j;
  const short8 zero8 = {0, 0, 0, 0, 0, 0, 0, 0};

  __syncthreads();

  for (int t = 0; t < SEQ_T; ++t) {
    const short* hc = hb[t & 1];
    short8 ah[4];
    #pragma unroll
    for (int kk = 0; kk < 4; ++kk)
      ah[kk] = aact ? *(const short8*)(hc + a_off + kk * 32) : zero8;

    // six independent depth-4 MFMA chains: {r,z,n} x {W_hi, W_lo}
    floatx4 aHr = {0.f,0.f,0.f,0.f}, aHz = {0.f,0.f,0.f,0.f}, aHn = {0.f,0.f,0.f,0.f};
    floatx4 aLr = {0.f,0.f,0.f,0.f}, aLz = {0.f,0.f,0.f,0.f}, aLn = {0.f,0.f,0.f,0.f};
    #pragma unroll
    for (int kk = 0; kk < 4; ++kk) {
      aHr = __builtin_amdgcn_mfma_f32_16x16x32_bf16(ah[kk], whi[0][kk], aHr, 0, 0, 0);
      aHz = __builtin_amdgcn_mfma_f32_16x16x32_bf16(ah[kk], whi[1][kk], aHz, 0, 0, 0);
      aHn = __builtin_amdgcn_mfma_f32_16x16x32_bf16(ah[kk], whi[2][kk], aHn, 0, 0, 0);
      aLr = __builtin_amdgcn_mfma_f32_16x16x32_bf16(ah[kk], wlo[0][kk], aLr, 0, 0, 0);
      aLz = __builtin_amdgcn_mfma_f32_16x16x32_bf16(ah[kk], wlo[1][kk], aLz, 0, 0, 0);
      aLn = __builtin_amdgcn_mfma_f32_16x16x32_bf16(ah[kk], wlo[2][kk], aLn, 0, 0, 0);
    }

    // C reg 0 = batch row quad, column j. Full wave active.
    const float xt = xs[t][quad];
    const float pr = fmaf(xt, wi_r, bi_r) + (aHr[0] + aLr[0]) + bh_r;
    const float pz = fmaf(xt, wi_z, bi_z) + (aHz[0] + aLz[0]) + bh_z;
    const float rg = __builtin_amdgcn_rcpf(1.0f + __expf(-pr));
    const float zg = __builtin_amdgcn_rcpf(1.0f + __expf(-pz));
    const float pn = fmaf(rg, (aHn[0] + aLn[0]) + bh_n, fmaf(xt, wi_n, bi_n));
    const float ng = 1.0f - 2.0f * __builtin_amdgcn_rcpf(1.0f + __expf(2.0f * pn));
    h = fmaf(zg, h - ng, ng);          // z*h + (1-z)*n
    hb[(t + 1) & 1][w_off] = bf16_of(h);
    __syncthreads();
  }

  // epilogue: logits = h @ Wfc^T + bfc (fp32), 4 rows x 10 outs
  hfin[quad][j] = h;
  __syncthreads();
  if (tid < 40) {
    const int r = tid / 10, o = tid - r * 10;
    float acc = bfc[o];
    #pragma unroll 4
    for (int k = 0; k < HID; ++k)
      acc = fmaf(hfin[r][k], Wfc[o * HID + k], acc);
    out[(size_t)(b0 + r) * 10 + o] = acc;
  }
}

extern "C" void kernel_launch(void* const* d_in, const int* in_sizes, int n_in,
                              void* d_out, int out_size, void* d_ws, size_t ws_size,
                              hipStream_t stream) {
  const float* x   = (const float*)d_in[0];
  const float* Wi  = (const float*)d_in[1];
  const float* bi  = (const float*)d_in[2];
  const float* Wh  = (const float*)d_in[3];
  const float* bh  = (const float*)d_in[4];
  const float* Wfc = (const float*)d_in[5];
  const float* bfc = (const float*)d_in[6];
  hipLaunchKernelGGL(gru_sparse4_w2, dim3(256), dim3(512), 0, stream,
                     x, Wi, bi, Wh, bh, Wfc, bfc, (float*)d_out);
}

// Round 9
// 339.551 us; speedup vs baseline: 3.3461x; 1.6004x over previous
//
#include <hip/hip_runtime.h>
#include <hip/hip_bf16.h>

#define SEQ_T 784
#define HID   128

typedef __attribute__((ext_vector_type(8))) short  short8;
typedef __attribute__((ext_vector_type(4))) float  floatx4;
typedef __attribute__((ext_vector_type(8))) float  float8;

// bf16 round-to-nearest-even on raw bits (inputs finite)
static __device__ __forceinline__ short bf16_of(float f) {
  union { float f; unsigned u; } v; v.f = f;
  return (short)((v.u + 0x7fffu + ((v.u >> 16) & 1u)) >> 16);
}
static __device__ __forceinline__ float f_of_bf16(short s) {
  union { unsigned u; float f; } v; v.u = ((unsigned)(unsigned short)s) << 16;
  return v.f;
}

// 256 blocks x 4 batch rows (1 block/CU). Batch row r at A-row 4r; C reg 0 of
// lane(quad,nn) = batch row quad, column j (R5 probe-verified map).
// SINGLE-PASS bf16 matmul (12 MFMA/wave/step, 466 cyc/SIMD floor).
// Precision ladder: R7 3-pass 4.9e-4, R8 2-pass (bf16 h) 9.8e-4; W-quant adds
// a similar ~5e-4 => expect ~1.5-2e-3 vs 3.0e-3 threshold.
// h lives in a 16-row zero-padded A-layout plane (stride 136 shorts): padding
// rows are never written after init, so A-fragment reads are UNCONDITIONAL
// ds_read_b128 (no per-element cndmask selects -- R8's VALU hotspot).
extern "C" __global__ void __launch_bounds__(512, 2)
gru_sparse4_1p(const float* __restrict__ x,    // [1024][784] fp32
               const float* __restrict__ Wi,   // [384]
               const float* __restrict__ bi,   // [384]
               const float* __restrict__ Wh,   // [384][128]
               const float* __restrict__ bh,   // [384]
               const float* __restrict__ Wfc,  // [10][128]
               const float* __restrict__ bfc,  // [10]
               float* __restrict__ out)        // [1024][10] fp32
{
  const int tid  = threadIdx.x;
  const int wv   = tid >> 6;
  const int lane = tid & 63;
  const int quad = lane >> 4;
  const int nn   = lane & 15;
  const int j    = (wv << 4) | nn;   // this lane's hidden column
  const int b0   = blockIdx.x * 4;   // 4 batch rows per block

  __shared__ __align__(16) float xs[SEQ_T][4];     // x fp32, [t][row]
  __shared__ __align__(16) short hb[2][16 * 136];  // h bf16, A-layout, dbuf
  __shared__ float hfin[4][HID];

  for (int i = tid; i < 2 * 16 * 136; i += 512) ((short*)hb)[i] = 0;
  for (int i = tid; i < 4 * SEQ_T; i += 512) {
    const int r = i / SEQ_T;
    const int t = i - r * SEQ_T;
    xs[t][r] = x[(size_t)(b0 + r) * SEQ_T + t];
  }

  // fp32 per-column gate constants; fold bi+bh (both biases are per-column)
  const float wi_r = Wi[j],  wi_z = Wi[HID + j],  wi_n = Wi[2 * HID + j];
  const float c_r  = bi[j] + bh[j];
  const float c_z  = bi[HID + j] + bh[HID + j];
  const float bi_n = bi[2 * HID + j];
  const float bh_n = bh[2 * HID + j];

  // Wh B-fragments, bf16 single-pass, register-resident.
  // Lane (quad,nn): B[k = kk*32 + quad*8 + e][n = nn] = Wh[j][k]
  short8 whi[3][4];
  #pragma unroll
  for (int g = 0; g < 3; ++g) {
    const float* wrow = Wh + (size_t)(g * HID + j) * HID;
    #pragma unroll
    for (int kk = 0; kk < 4; ++kk) {
      float8 w = *(const float8*)(wrow + kk * 32 + quad * 8);
      short8 hi;
      #pragma unroll
      for (int e = 0; e < 8; ++e) hi[e] = bf16_of(w[e]);
      whi[g][kk] = hi;
    }
  }

  float h = 0.0f;                          // h[batch=quad][j], fp32 carry
  const int a_off = nn * 136 + quad * 8;   // + kk*32 (shorts): A[m=nn][k]
  const int w_off = (quad * 4) * 136 + j;  // batch row quad at A-row 4*quad

  __syncthreads();

  for (int t = 0; t < SEQ_T; ++t) {
    const short* hc = hb[t & 1];
    short8 ah[4];
    #pragma unroll
    for (int kk = 0; kk < 4; ++kk)
      ah[kk] = *(const short8*)(hc + a_off + kk * 32);  // unconditional: pad rows are zero

    floatx4 ar = {0.f, 0.f, 0.f, 0.f};
    floatx4 az = {0.f, 0.f, 0.f, 0.f};
    floatx4 an = {0.f, 0.f, 0.f, 0.f};
    #pragma unroll
    for (int kk = 0; kk < 4; ++kk) {   // three independent depth-4 chains
      ar = __builtin_amdgcn_mfma_f32_16x16x32_bf16(ah[kk], whi[0][kk], ar, 0, 0, 0);
      az = __builtin_amdgcn_mfma_f32_16x16x32_bf16(ah[kk], whi[1][kk], az, 0, 0, 0);
      an = __builtin_amdgcn_mfma_f32_16x16x32_bf16(ah[kk], whi[2][kk], an, 0, 0, 0);
    }

    // C reg 0 = batch row quad, column j. Full wave active.
    const float xt = xs[t][quad];
    const float pr = fmaf(xt, wi_r, c_r) + ar[0];
    const float pz = fmaf(xt, wi_z, c_z) + az[0];
    const float rg = __builtin_amdgcn_rcpf(1.0f + __expf(-pr));
    const float zg = __builtin_amdgcn_rcpf(1.0f + __expf(-pz));
    const float pn = fmaf(rg, an[0] + bh_n, fmaf(xt, wi_n, bi_n));
    const float ng = 1.0f - 2.0f * __builtin_amdgcn_rcpf(1.0f + __expf(2.0f * pn));
    h = fmaf(zg, h - ng, ng);          // z*h + (1-z)*n
    hb[(t + 1) & 1][w_off] = bf16_of(h);
    __syncthreads();
  }

  // epilogue: logits = h @ Wfc^T + bfc (fp32), 4 rows x 10 outs
  hfin[quad][j] = h;
  __syncthreads();
  if (tid < 40) {
    const int r = tid / 10, o = tid - r * 10;
    float acc = bfc[o];
    #pragma unroll 4
    for (int k = 0; k < HID; ++k)
      acc = fmaf(hfin[r][k], Wfc[o * HID + k], acc);
    out[(size_t)(b0 + r) * 10 + o] = acc;
  }
}

extern "C" void kernel_launch(void* const* d_in, const int* in_sizes, int n_in,
                              void* d_out, int out_size, void* d_ws, size_t ws_size,
                              hipStream_t stream) {
  const float* x   = (const float*)d_in[0];
  const float* Wi  = (const float*)d_in[1];
  const float* bi  = (const float*)d_in[2];
  const float* Wh  = (const float*)d_in[3];
  const float* bh  = (const float*)d_in[4];
  const float* Wfc = (const float*)d_in[5];
  const float* bfc = (const float*)d_in[6];
  hipLaunchKernelGGL(gru_sparse4_1p, dim3(256), dim3(512), 0, stream,
                     x, Wi, bi, Wh, bh, Wfc, bfc, (float*)d_out);
}

// Round 10
// 335.121 us; speedup vs baseline: 3.3903x; 1.0132x over previous
//
#include <hip/hip_runtime.h>
#include <hip/hip_bf16.h>

#define SEQ_T 784
#define HID   128
#define S_H   152   // h-plane stride in shorts: 76 dwords == 12 mod 32 -> 2-way max (free); 304B = 16B-aligned

typedef __attribute__((ext_vector_type(8))) short  short8;
typedef __attribute__((ext_vector_type(4))) float  floatx4;
typedef __attribute__((ext_vector_type(8))) float  float8;

// bf16 round-to-nearest-even on raw bits (inputs finite)
static __device__ __forceinline__ short bf16_of(float f) {
  union { float f; unsigned u; } v; v.f = f;
  return (short)((v.u + 0x7fffu + ((v.u >> 16) & 1u)) >> 16);
}

#define MFMA_BF16 __builtin_amdgcn_mfma_f32_16x16x32_bf16

// 256 blocks x 4 batch rows (1 block/CU; grid pins occupancy, so latency must
// be minimized, not hidden). Batch row r at A-row 4r; C reg 0 of lane(quad,nn)
// = batch row quad, column j (R5 probe-verified). Single-pass bf16 (R9:
// absmax 9.77e-4 -- W-quant measured free). R10 tail surgery:
//  - two depth-2 MFMA chains per gate (was depth-4) -> less serial latency
//  - stride 152 kills the 8-way bank groups of stride 136 (R9: 2.6e7 conflicts)
//  - t-loop unrolled x2 -> no buffer-flip selects
extern "C" __global__ void __launch_bounds__(512, 2)
gru_sparse4_t(const float* __restrict__ x,    // [1024][784] fp32
              const float* __restrict__ Wi,   // [384]
              const float* __restrict__ bi,   // [384]
              const float* __restrict__ Wh,   // [384][128]
              const float* __restrict__ bh,   // [384]
              const float* __restrict__ Wfc,  // [10][128]
              const float* __restrict__ bfc,  // [10]
              float* __restrict__ out)        // [1024][10] fp32
{
  const int tid  = threadIdx.x;
  const int wv   = tid >> 6;
  const int lane = tid & 63;
  const int quad = lane >> 4;
  const int nn   = lane & 15;
  const int j    = (wv << 4) | nn;   // this lane's hidden column
  const int b0   = blockIdx.x * 4;   // 4 batch rows per block

  __shared__ __align__(16) float xs[SEQ_T][4];      // x fp32, [t][row]
  __shared__ __align__(16) short hb[2][16 * S_H];   // h bf16, A-layout, dbuf
  __shared__ float hfin[4][HID];

  for (int i = tid; i < 2 * 16 * S_H; i += 512) ((short*)hb)[i] = 0;
  for (int i = tid; i < 4 * SEQ_T; i += 512) {
    const int r = i / SEQ_T;
    const int t = i - r * SEQ_T;
    xs[t][r] = x[(size_t)(b0 + r) * SEQ_T + t];
  }

  // fp32 per-column gate constants; fold bi+bh for r,z
  const float wi_r = Wi[j],  wi_z = Wi[HID + j],  wi_n = Wi[2 * HID + j];
  const float c_r  = bi[j] + bh[j];
  const float c_z  = bi[HID + j] + bh[HID + j];
  const float bi_n = bi[2 * HID + j];
  const float bh_n = bh[2 * HID + j];

  // Wh B-fragments, bf16 single-pass, register-resident.
  // Lane (quad,nn): B[k = kk*32 + quad*8 + e][n = nn] = Wh[j][k]
  short8 whi[3][4];
  #pragma unroll
  for (int g = 0; g < 3; ++g) {
    const float* wrow = Wh + (size_t)(g * HID + j) * HID;
    #pragma unroll
    for (int kk = 0; kk < 4; ++kk) {
      float8 w = *(const float8*)(wrow + kk * 32 + quad * 8);
      short8 hi;
      #pragma unroll
      for (int e = 0; e < 8; ++e) hi[e] = bf16_of(w[e]);
      whi[g][kk] = hi;
    }
  }

  float h = 0.0f;                          // h[batch=quad][j], fp32 carry
  const int a_off = nn * S_H + quad * 8;   // + kk*32 (shorts): A[m=nn][k]
  const int w_off = (quad * 4) * S_H + j;  // batch row quad at A-row 4*quad

  __syncthreads();

  auto step = [&](const short* __restrict__ hc, short* __restrict__ nx, int t) {
    short8 ah[4];
    #pragma unroll
    for (int kk = 0; kk < 4; ++kk)
      ah[kk] = *(const short8*)(hc + a_off + kk * 32);  // pad rows are zero

    // two independent depth-2 MFMA chains per gate
    floatx4 r0 = {0.f,0.f,0.f,0.f}, r1 = {0.f,0.f,0.f,0.f};
    floatx4 z0 = {0.f,0.f,0.f,0.f}, z1 = {0.f,0.f,0.f,0.f};
    floatx4 n0 = {0.f,0.f,0.f,0.f}, n1 = {0.f,0.f,0.f,0.f};
    r0 = MFMA_BF16(ah[0], whi[0][0], r0, 0, 0, 0);
    z0 = MFMA_BF16(ah[0], whi[1][0], z0, 0, 0, 0);
    n0 = MFMA_BF16(ah[0], whi[2][0], n0, 0, 0, 0);
    r1 = MFMA_BF16(ah[1], whi[0][1], r1, 0, 0, 0);
    z1 = MFMA_BF16(ah[1], whi[1][1], z1, 0, 0, 0);
    n1 = MFMA_BF16(ah[1], whi[2][1], n1, 0, 0, 0);
    r0 = MFMA_BF16(ah[2], whi[0][2], r0, 0, 0, 0);
    z0 = MFMA_BF16(ah[2], whi[1][2], z0, 0, 0, 0);
    n0 = MFMA_BF16(ah[2], whi[2][2], n0, 0, 0, 0);
    r1 = MFMA_BF16(ah[3], whi[0][3], r1, 0, 0, 0);
    z1 = MFMA_BF16(ah[3], whi[1][3], z1, 0, 0, 0);
    n1 = MFMA_BF16(ah[3], whi[2][3], n1, 0, 0, 0);

    // C reg 0 = batch row quad, column j. Full wave active.
    const float xt = xs[t][quad];
    const float pr = fmaf(xt, wi_r, c_r) + (r0[0] + r1[0]);
    const float pz = fmaf(xt, wi_z, c_z) + (z0[0] + z1[0]);
    const float rg = __builtin_amdgcn_rcpf(1.0f + __expf(-pr));
    const float zg = __builtin_amdgcn_rcpf(1.0f + __expf(-pz));
    const float pn = fmaf(rg, (n0[0] + n1[0]) + bh_n, fmaf(xt, wi_n, bi_n));
    const float ng = 1.0f - 2.0f * __builtin_amdgcn_rcpf(1.0f + __expf(2.0f * pn));
    h = fmaf(zg, h - ng, ng);          // z*h + (1-z)*n
    nx[w_off] = bf16_of(h);
  };

  for (int t = 0; t < SEQ_T; t += 2) {
    step(hb[0], hb[1], t);
    __syncthreads();
    step(hb[1], hb[0], t + 1);
    __syncthreads();
  }

  // epilogue: logits = h @ Wfc^T + bfc (fp32), 4 rows x 10 outs
  hfin[quad][j] = h;
  __syncthreads();
  if (tid < 40) {
    const int r = tid / 10, o = tid - r * 10;
    float acc = bfc[o];
    #pragma unroll 4
    for (int k = 0; k < HID; ++k)
      acc = fmaf(hfin[r][k], Wfc[o * HID + k], acc);
    out[(size_t)(b0 + r) * 10 + o] = acc;
  }
}

extern "C" void kernel_launch(void* const* d_in, const int* in_sizes, int n_in,
                              void* d_out, int out_size, void* d_ws, size_t ws_size,
                              hipStream_t stream) {
  const float* x   = (const float*)d_in[0];
  const float* Wi  = (const float*)d_in[1];
  const float* bi  = (const float*)d_in[2];
  const float* Wh  = (const float*)d_in[3];
  const float* bh  = (const float*)d_in[4];
  const float* Wfc = (const float*)d_in[5];
  const float* bfc = (const float*)d_in[6];
  hipLaunchKernelGGL(gru_sparse4_t, dim3(256), dim3(512), 0, stream,
                     x, Wi, bi, Wh, bh, Wfc, bfc, (float*)d_out);
}